// Round 9
// baseline (462.166 us; speedup 1.0000x reference)
//
#include <hip/hip_runtime.h>
#include <hip/hip_bf16.h>
#include <hip/hip_cooperative_groups.h>
#include <math.h>

namespace cg = cooperative_groups;

#define Tn   8192
#define Hn   1024
#define En   8
#define DFFn 4096

typedef __attribute__((ext_vector_type(8))) short bf16x8;           // 8 bf16 = 4 VGPRs
typedef __attribute__((ext_vector_type(8))) unsigned short u16x8;   // 16 B
typedef __attribute__((ext_vector_type(4))) float f32x4;

static __device__ inline unsigned short f2bf(float f) {
    __hip_bfloat16 h = __float2bfloat16(f);
    return __builtin_bit_cast(unsigned short, h);
}

static __device__ inline bf16x8 ldsfrag(const char* base, int row, int chunk) {
    return *(const bf16x8*)(base + row * 128 + (((chunk) ^ (row & 7)) << 4));
}

// ======================= fused MoE (cooperative) ==========================
// 256 blocks x 512 thr, 128KB dyn LDS -> exactly 1 block/CU (coop-safe).
// Phase A: per block {1 W1 128x128 transpose tile, 1 W2 tile, 32 gate toks}
// grid.sync ; block0 reduces aux ; Phase B: gemm0 (r1-exact form, 2 tiles
// per block, full drain between) ; grid.sync ; Phase C: gemm1 (r4 form).
// Eliminates all inter-dispatch gaps + the aux tail round.
__global__ __launch_bounds__(512, 2) void moe_fused(
    const float* __restrict__ x,  const float* __restrict__ gW,
    const float* __restrict__ gb, const float* __restrict__ W1,
    const float* __restrict__ b1, const float* __restrict__ W2,
    const float* __restrict__ b2,
    unsigned short* __restrict__ W1t, unsigned short* __restrict__ W2t,
    unsigned short* __restrict__ xbf, unsigned short* __restrict__ hdd,
    float* __restrict__ tokw, float* __restrict__ pb_load,
    int* __restrict__ pb_cnt, float* __restrict__ out,
    float* __restrict__ out_tail)
{
    extern __shared__ char lds[];
    const int tid = threadIdx.x;
    const int bid = blockIdx.x;
    const int lane = tid & 63;
    const int wid  = tid >> 6;
    const int fr   = lane & 15;
    const int fq   = lane >> 4;
    const int sr   = tid >> 3;                 // staging row 0..63
    const int scq  = (tid & 7) ^ (sr & 7);     // pre-swizzled k-chunk

    // ===================== Phase A: prep =====================
    {   // A1/A2: W1 then W2 128x128 transpose tile (tile index = bid)
        unsigned short* tile = (unsigned short*)lds;   // [128][128] swizzled
        #pragma unroll
        for (int pass = 0; pass < 2; ++pass) {
            const float* src = pass ? W2 : W1;
            unsigned short* dst = pass ? W2t : W1t;
            const int SR = pass ? DFFn : Hn, SC = pass ? Hn : DFFn;
            const int tcs = SC >> 7;
            const int tr = bid / tcs, tc = bid - tr * tcs;
            const int r0 = tr << 7, c0 = tc << 7;
            #pragma unroll
            for (int i = 0; i < 8; ++i) {
                int idx = tid + i * 512;
                int r = idx >> 5, c4 = (idx & 31) << 2;
                float4 v = *(const float4*)(src + (size_t)(r0 + r) * SC + c0 + c4);
                int cs = c4 ^ (((r >> 3) & 7) << 2);
                ushort4 pk;
                pk.x = f2bf(v.x); pk.y = f2bf(v.y);
                pk.z = f2bf(v.z); pk.w = f2bf(v.w);
                *(ushort4*)(tile + r * 128 + cs) = pk;
            }
            __syncthreads();
            #pragma unroll
            for (int i = 0; i < 4; ++i) {
                int idx = tid + i * 512;
                int n = idx >> 4, kg = idx & 15, k0 = kg << 3;
                int s = (kg & 7) << 2;
                u16x8 o;
                #pragma unroll
                for (int j = 0; j < 8; ++j)
                    o[j] = tile[(k0 + j) * 128 + (n ^ s)];
                *(u16x8*)(dst + (size_t)(c0 + n) * SR + r0 + k0) = o;
            }
            __syncthreads();
        }

        // A3: gate + x->bf16 for 32 tokens
        float* gwt    = (float*)lds;                   // 32 KB
        float* s_load = (float*)(lds + 32768);
        int*   s_cnt  = (int*)(lds + 32768 + 64);
        if (tid < En) { s_load[tid] = 0.f; s_cnt[tid] = 0; }
        #pragma unroll
        for (int i = 0; i < 4; ++i) {                  // 2048 float4
            int f4 = tid + i * 512;
            float4 v = ((const float4*)gW)[f4];
            int f = f4 << 2;
            gwt[((f + 0) & 7) * 1024 + ((f + 0) >> 3)] = v.x;
            gwt[((f + 1) & 7) * 1024 + ((f + 1) >> 3)] = v.y;
            gwt[((f + 2) & 7) * 1024 + ((f + 2) >> 3)] = v.z;
            gwt[((f + 3) & 7) * 1024 + ((f + 3) >> 3)] = v.w;
        }
        __syncthreads();
        #pragma unroll
        for (int t = 0; t < 4; ++t) {
            const int tok = bid * 32 + wid + t * 8;
            const float4* xr = (const float4*)(x + (size_t)tok * Hn);
            float acc[8] = {0.f,0.f,0.f,0.f,0.f,0.f,0.f,0.f};
            #pragma unroll
            for (int j = 0; j < Hn / 256; ++j) {
                int h4 = j * 64 + lane;
                float4 xv = xr[h4];
                ushort4 pk;
                pk.x = f2bf(xv.x); pk.y = f2bf(xv.y);
                pk.z = f2bf(xv.z); pk.w = f2bf(xv.w);
                ((ushort4*)xbf)[(size_t)tok * (Hn / 4) + h4] = pk;
                #pragma unroll
                for (int e = 0; e < 8; ++e) {
                    const float4 w = *(const float4*)(gwt + e * 1024 + h4 * 4);
                    acc[e] += xv.x * w.x + xv.y * w.y + xv.z * w.z + xv.w * w.w;
                }
            }
            #pragma unroll
            for (int e = 0; e < 8; ++e) {
                float v = acc[e];
                #pragma unroll
                for (int off = 32; off > 0; off >>= 1) v += __shfl_xor(v, off, 64);
                acc[e] = v + gb[e];
            }
            if (lane == 0) {
                #pragma unroll
                for (int e = 0; e < 8; ++e) atomicAdd(&s_load[e], acc[e]);
                int i1 = 0; float v1 = acc[0];
                #pragma unroll
                for (int e = 1; e < 8; ++e) if (acc[e] > v1) { v1 = acc[e]; i1 = e; }
                int i2 = -1; float v2 = -3.0e38f;
                #pragma unroll
                for (int e = 0; e < 8; ++e) if (e != i1 && acc[e] > v2) { v2 = acc[e]; i2 = e; }
                atomicAdd(&s_cnt[i1], 1);
                atomicAdd(&s_cnt[i2], 1);
                float e2 = __expf(v2 - v1);
                float tt = 1.0f + e2;
                tokw[tok] = 1.0f / tt + e2 / tt;
            }
        }
        __syncthreads();
        if (tid < En) {
            pb_load[bid * En + tid] = s_load[tid];
            pb_cnt [bid * En + tid] = s_cnt[tid];
        }
    }

    __threadfence();
    cg::this_grid().sync();

    // ---- aux reduce (block 0 only, ~1us) ----
    if (bid == 0) {
        float* sl = (float*)lds;
        int*   scp = (int*)(lds + 64);
        if (tid < En) { sl[tid] = 0.f; scp[tid] = 0; }
        __syncthreads();
        const int e = tid & 7;
        float p = 0.f; int c = 0;
        for (int g2 = tid >> 3; g2 < 256; g2 += 64) {
            p += pb_load[g2 * En + e];
            c += pb_cnt [g2 * En + e];
        }
        atomicAdd(&sl[e], p);
        atomicAdd(&scp[e], c);
        __syncthreads();
        if (tid == 0) {
            float aux = 0.f;
            #pragma unroll
            for (int e2 = 0; e2 < En; ++e2) {
                float m = sl[e2] * (1.0f / (float)Tn);
                aux += m * m;
            }
            out_tail[0] = aux;
            #pragma unroll
            for (int e2 = 0; e2 < En; ++e2) out_tail[1 + e2] = (float)scp[e2];
        }
        __syncthreads();
    }

#define SBARR do { \
    __builtin_amdgcn_sched_barrier(0); \
    __builtin_amdgcn_s_barrier(); \
    __builtin_amdgcn_sched_barrier(0); } while (0)
#define MIDSYNC do { \
    __builtin_amdgcn_sched_barrier(0); \
    __builtin_amdgcn_s_barrier(); \
    asm volatile("s_waitcnt lgkmcnt(0)" ::: "memory"); \
    __builtin_amdgcn_sched_barrier(0); } while (0)
#define WAITL(n) do { \
    asm volatile("s_waitcnt lgkmcnt(" #n ")" ::: "memory"); \
    __builtin_amdgcn_sched_barrier(0); } while (0)
#define VMC(n) do { asm volatile("s_waitcnt vmcnt(" #n ")" ::: "memory"); \
    __builtin_amdgcn_sched_barrier(0); } while (0)
#define PRIO1 __builtin_amdgcn_s_setprio(1)
#define PRIO0 __builtin_amdgcn_s_setprio(0)

    // ===================== Phase B: gemm0 (r1-exact, 2 tiles) =============
    {
        constexpr int ABY = 256 * 64 * 2;     // 32 KB
        constexpr int TLB = ABY + ABY;        // 64 KB per K-tile buffer
        const int wn = wid & 3, wm = wid >> 2;
        const int wrow = wm * 128, wcol = wn * 64;

        bf16x8 af[4][2], bfr[4][2];
        f32x4  acc[8][4];
        const f32x4 zero = {0.f, 0.f, 0.f, 0.f};

#define STA0(b, u, kt) __builtin_amdgcn_global_load_lds( \
    (const __attribute__((address_space(1))) void*)(xbf + aOff[u] + (unsigned)(kt) * 64u), \
    (__attribute__((address_space(3))) void*)(lds + (b) * TLB + (u) * 8192 + tid * 16), 16, 0, 0)
#define STB0(b, u, kt) __builtin_amdgcn_global_load_lds( \
    (const __attribute__((address_space(1))) void*)(W1t + bOff[u] + (unsigned)(kt) * 64u), \
    (__attribute__((address_space(3))) void*)(lds + (b) * TLB + ABY + (u) * 8192 + tid * 16), 16, 0, 0)
#define RDA0(b, half) do { _Pragma("unroll") \
    for (int m_ = 0; m_ < 4; ++m_) { _Pragma("unroll") \
        for (int ks_ = 0; ks_ < 2; ++ks_) \
            af[m_][ks_] = ldsfrag(lds + (b) * TLB, \
                wrow + ((half) * 4 + m_) * 16 + fr, ks_ * 4 + fq); } } while (0)
#define RDB0(b, half) do { _Pragma("unroll") \
    for (int n_ = 0; n_ < 2; ++n_) { _Pragma("unroll") \
        for (int ks_ = 0; ks_ < 2; ++ks_) \
            bfr[(half) * 2 + n_][ks_] = ldsfrag(lds + (b) * TLB + ABY, \
                wcol + ((half) * 2 + n_) * 16 + fr, ks_ * 4 + fq); } } while (0)
#define MFMAQ0(hm, hn) do { \
    PRIO1; \
    _Pragma("unroll") \
    for (int m_ = 0; m_ < 4; ++m_) { _Pragma("unroll") \
        for (int n_ = 0; n_ < 2; ++n_) { _Pragma("unroll") \
            for (int ks_ = 0; ks_ < 2; ++ks_) \
                acc[(hm) * 4 + m_][(hn) * 2 + n_] = \
                    __builtin_amdgcn_mfma_f32_16x16x32_bf16( \
                        af[m_][ks_], bfr[(hn) * 2 + n_][ks_], \
                        acc[(hm) * 4 + m_][(hn) * 2 + n_], 0, 0, 0); } } \
    PRIO0; } while (0)

        for (int tt = 0; tt < 2; ++tt) {
            const int g   = bid + tt * 256;
            const int xcd = g & 7;
            const int wg  = xcd * 64 + (g >> 3);    // bijective over 512
            const int by  = wg >> 4, bx = wg & 15;
            const int m0  = by * 256, n0 = bx * 256;

            unsigned aOff[4], bOff[4];
            #pragma unroll
            for (int u = 0; u < 4; ++u) {
                aOff[u] = (unsigned)((m0 + u * 64 + sr) * Hn + scq * 8);
                bOff[u] = (unsigned)((n0 + u * 64 + sr) * Hn + scq * 8);
            }
            #pragma unroll
            for (int i = 0; i < 8; ++i)
                #pragma unroll
                for (int j = 0; j < 4; ++j) acc[i][j] = zero;

            STA0(0,0,0); STA0(0,1,0); STA0(0,2,0); STA0(0,3,0);
            STB0(0,0,0); STB0(0,1,0); STB0(0,2,0); STB0(0,3,0);
            STA0(1,0,1); STA0(1,2,1);
            STB0(1,0,1); STB0(1,1,1); STB0(1,2,1); STB0(1,3,1);
            VMC(6);
            __builtin_amdgcn_s_barrier();
            __builtin_amdgcn_sched_barrier(0);

            const int KT = Hn >> 6;                 // 16
            for (int i = 0; i < (KT >> 1); ++i) {
                const int t1 = 2 * i + 1;
                const int c2 = (2 * i + 2 < KT) ? 2 * i + 2 : KT - 1;
                const int c3 = (2 * i + 3 < KT) ? 2 * i + 3 : KT - 1;

                RDA0(0, 0); RDB0(0, 0);
                STA0(1,1,t1); STA0(1,3,t1);
                MIDSYNC; MFMAQ0(0, 0); SBARR;

                RDB0(0, 1);
                STA0(0,0,c2); STA0(0,2,c2);
                MIDSYNC; MFMAQ0(0, 1); SBARR;

                RDA0(0, 1);
                STB0(0,0,c2); STB0(0,1,c2);
                MIDSYNC; MFMAQ0(1, 0); SBARR;

                STB0(0,2,c2); STB0(0,3,c2);
                MIDSYNC; MFMAQ0(1, 1); VMC(6); SBARR;

                RDA0(1, 0); RDB0(1, 0);
                STA0(0,1,c2); STA0(0,3,c2);
                MIDSYNC; MFMAQ0(0, 0); SBARR;

                RDB0(1, 1);
                STA0(1,0,c3); STA0(1,2,c3);
                MIDSYNC; MFMAQ0(0, 1); SBARR;

                RDA0(1, 1);
                STB0(1,0,c3); STB0(1,1,c3);
                MIDSYNC; MFMAQ0(1, 0); SBARR;

                STB0(1,2,c3); STB0(1,3,c3);
                MIDSYNC; MFMAQ0(1, 1); VMC(6); SBARR;
            }

            // epilogue: col = lane&15, row = (lane>>4)*4 + reg; gelu -> hdd
            float bias4[4];
            #pragma unroll
            for (int ni = 0; ni < 4; ++ni)
                bias4[ni] = b1[n0 + wcol + ni * 16 + fr];
            #pragma unroll
            for (int mi = 0; mi < 8; ++mi) {
                #pragma unroll
                for (int ni = 0; ni < 4; ++ni) {
                    const int col = n0 + wcol + ni * 16 + fr;
                    const int rb  = m0 + wrow + mi * 16 + fq * 4;
                    #pragma unroll
                    for (int i2 = 0; i2 < 4; ++i2) {
                        float u  = acc[mi][ni][i2] + bias4[ni];
                        float uu = u * u;
                        float z  = u * __fmaf_rn(uu, -0.07135607f, -1.59576912f);
                        float e  = __expf(z);
                        float gg = u * __builtin_amdgcn_rcpf(1.0f + e);
                        hdd[(size_t)(rb + i2) * DFFn + col] = f2bf(gg);
                    }
                }
            }
            if (tt == 0) {   // drain stale clamped stages before LDS reuse
                asm volatile("s_waitcnt vmcnt(0)" ::: "memory");
                __builtin_amdgcn_sched_barrier(0);
                SBARR;
            }
        }
#undef STA0
#undef STB0
#undef RDA0
#undef RDB0
#undef MFMAQ0
    }

    __threadfence();
    cg::this_grid().sync();

    // ===================== Phase C: gemm1 (r4 form) =======================
    {
        constexpr int ABY = 256 * 64 * 2;     // 32 KB
        constexpr int BBY = 128 * 64 * 2;     // 16 KB
        constexpr int TLB = ABY + BBY;        // 48 KB
        const int wn = wid & 1, wm = wid >> 1;
        const int wrow = wm * 64, wcol = wn * 64;

        bf16x8 af[2][2], bfr[4][2];
        f32x4  acc[4][4];
        const f32x4 zero = {0.f, 0.f, 0.f, 0.f};
        #pragma unroll
        for (int i = 0; i < 4; ++i)
            #pragma unroll
            for (int j = 0; j < 4; ++j) acc[i][j] = zero;

        const int g   = bid;
        const int xcd = g & 7;
        const int wg  = xcd * 32 + (g >> 3);        // bijective over 256
        const int by  = wg >> 3, bx = wg & 7;
        const int m0  = by * 256, n0 = bx * 128;

        unsigned aOff[4], bOff[2];
        #pragma unroll
        for (int u = 0; u < 4; ++u)
            aOff[u] = (unsigned)((m0 + u * 64 + sr) * DFFn + scq * 8);
        #pragma unroll
        for (int u = 0; u < 2; ++u)
            bOff[u] = (unsigned)((n0 + u * 64 + sr) * DFFn + scq * 8);

#define STA1(b, u, kt) __builtin_amdgcn_global_load_lds( \
    (const __attribute__((address_space(1))) void*)(hdd + aOff[u] + (unsigned)(kt) * 64u), \
    (__attribute__((address_space(3))) void*)(lds + (b) * TLB + (u) * 8192 + tid * 16), 16, 0, 0)
#define STB1(b, u, kt) __builtin_amdgcn_global_load_lds( \
    (const __attribute__((address_space(1))) void*)(W2t + bOff[u] + (unsigned)(kt) * 64u), \
    (__attribute__((address_space(3))) void*)(lds + (b) * TLB + ABY + (u) * 8192 + tid * 16), 16, 0, 0)
#define RD_A1(b, half, m_) do { _Pragma("unroll") \
    for (int ks_ = 0; ks_ < 2; ++ks_) \
        af[m_][ks_] = ldsfrag(lds + (b) * TLB, \
            wrow + ((half) * 2 + (m_)) * 16 + fr, ks_ * 4 + fq); } while (0)
#define RD_B1(b, nn) do { _Pragma("unroll") \
    for (int ks_ = 0; ks_ < 2; ++ks_) \
        bfr[nn][ks_] = ldsfrag(lds + (b) * TLB + ABY, \
            wcol + (nn) * 16 + fr, ks_ * 4 + fq); } while (0)
#define MFMA1_N(hm, nn) do { _Pragma("unroll") \
    for (int m_ = 0; m_ < 2; ++m_) { _Pragma("unroll") \
        for (int ks_ = 0; ks_ < 2; ++ks_) \
            acc[(hm) * 2 + m_][nn] = \
                __builtin_amdgcn_mfma_f32_16x16x32_bf16( \
                    bfr[nn][ks_], af[m_][ks_], \
                    acc[(hm) * 2 + m_][nn], 0, 0, 0); } } while (0)
#define MFMA1_M(hm, m_) do { _Pragma("unroll") \
    for (int n_ = 0; n_ < 4; ++n_) { _Pragma("unroll") \
        for (int ks_ = 0; ks_ < 2; ++ks_) \
            acc[(hm) * 2 + (m_)][n_] = \
                __builtin_amdgcn_mfma_f32_16x16x32_bf16( \
                    bfr[n_][ks_], af[m_][ks_], \
                    acc[(hm) * 2 + (m_)][n_], 0, 0, 0); } } while (0)

        STA1(0,0,0); STA1(0,1,0); STA1(0,2,0); STA1(0,3,0);
        STB1(0,0,0); STB1(0,1,0);
        STB1(1,0,1); STB1(1,1,1);
        VMC(2);
        __builtin_amdgcn_s_barrier();
        __builtin_amdgcn_sched_barrier(0);

        const int KT = DFFn >> 6;                   // 64
        for (int i = 0; i < (KT >> 1); ++i) {
            const int t1 = 2 * i + 1;
            const int c2 = (2 * i + 2 < KT) ? 2 * i + 2 : KT - 1;
            const int c3 = (2 * i + 3 < KT) ? 2 * i + 3 : KT - 1;

            RD_A1(0,0,0); RD_A1(0,0,1);
            RD_B1(0,0); RD_B1(0,1); RD_B1(0,2); RD_B1(0,3);
            STA1(1,0,t1); STA1(1,1,t1); STA1(1,2,t1); STA1(1,3,t1);
            SBARR; PRIO1;
            WAITL(6); MFMA1_N(0,0);
            WAITL(4); MFMA1_N(0,1);
            WAITL(2); MFMA1_N(0,2);
            WAITL(0); MFMA1_N(0,3);
            PRIO0; SBARR;

            RD_A1(0,1,0); RD_A1(0,1,1);
            STB1(0,0,c2); STB1(0,1,c2);
            SBARR; PRIO1;
            WAITL(2); MFMA1_M(1,0);
            WAITL(0); MFMA1_M(1,1);
            PRIO0; VMC(2); SBARR;

            RD_A1(1,0,0); RD_A1(1,0,1);
            RD_B1(1,0); RD_B1(1,1); RD_B1(1,2); RD_B1(1,3);
            STA1(0,0,c2); STA1(0,1,c2); STA1(0,2,c2); STA1(0,3,c2);
            SBARR; PRIO1;
            WAITL(6); MFMA1_N(0,0);
            WAITL(4); MFMA1_N(0,1);
            WAITL(2); MFMA1_N(0,2);
            WAITL(0); MFMA1_N(0,3);
            PRIO0; SBARR;

            RD_A1(1,1,0); RD_A1(1,1,1);
            STB1(1,0,c3); STB1(1,1,c3);
            SBARR; PRIO1;
            WAITL(2); MFMA1_M(1,0);
            WAITL(0); MFMA1_M(1,1);
            PRIO0; VMC(2); SBARR;
        }

        // epilogue (swapped D): M = lane&15, N = (lane>>4)*4+reg -> float4
        const int mrow0 = m0 + wrow + fr;
        const int ncol0 = n0 + wcol + fq * 4;
        float4 b4[4];
        #pragma unroll
        for (int ni = 0; ni < 4; ++ni)
            b4[ni] = *(const float4*)(b2 + ncol0 + ni * 16);

        #pragma unroll
        for (int mi = 0; mi < 4; ++mi) {
            const int row = mrow0 + mi * 16;
            const float tw = tokw[row];
            #pragma unroll
            for (int ni = 0; ni < 4; ++ni) {
                f32x4 v = acc[mi][ni];
                float4 o;
                o.x = (v[0] + b4[ni].x) * tw;
                o.y = (v[1] + b4[ni].y) * tw;
                o.z = (v[2] + b4[ni].z) * tw;
                o.w = (v[3] + b4[ni].w) * tw;
                *(float4*)(out + (size_t)row * Hn + ncol0 + ni * 16) = o;
            }
        }
#undef STA1
#undef STB1
#undef RD_A1
#undef RD_B1
#undef MFMA1_N
#undef MFMA1_M
    }
#undef SBARR
#undef MIDSYNC
#undef WAITL
#undef VMC
#undef PRIO1
#undef PRIO0
}

extern "C" void kernel_launch(void* const* d_in, const int* in_sizes, int n_in,
                              void* d_out, int out_size, void* d_ws, size_t ws_size,
                              hipStream_t stream)
{
    const float* x  = (const float*)d_in[0];
    const float* gW = (const float*)d_in[1];
    const float* gb = (const float*)d_in[2];
    const float* W1 = (const float*)d_in[3];
    const float* b1 = (const float*)d_in[4];
    const float* W2 = (const float*)d_in[5];
    const float* b2 = (const float*)d_in[6];
    float* out = (float*)d_out;

    char* ws = (char*)d_ws;
    unsigned short* xbf = (unsigned short*)ws;  ws += (size_t)Tn * Hn * 2;
    unsigned short* W1t = (unsigned short*)ws;  ws += (size_t)Hn * DFFn * 2;
    unsigned short* W2t = (unsigned short*)ws;  ws += (size_t)Hn * DFFn * 2;
    unsigned short* hdd = (unsigned short*)ws;  ws += (size_t)Tn * DFFn * 2;
    float* tokw     = (float*)ws;               ws += (size_t)Tn * 4;
    float* pb_load  = (float*)ws;               ws += 256 * En * 4;
    int*   pb_cnt   = (int*)ws;                 ws += 256 * En * 4;
    float* out_tail = out + (size_t)Tn * Hn;

    static bool attr_done = false;
    if (!attr_done) {
        (void)hipFuncSetAttribute(
            reinterpret_cast<const void*>(&moe_fused),
            hipFuncAttributeMaxDynamicSharedMemorySize, 131072);
        attr_done = true;
    }

    void* kargs[] = {
        (void*)&x, (void*)&gW, (void*)&gb, (void*)&W1, (void*)&b1,
        (void*)&W2, (void*)&b2, (void*)&W1t, (void*)&W2t, (void*)&xbf,
        (void*)&hdd, (void*)&tokw, (void*)&pb_load, (void*)&pb_cnt,
        (void*)&out, (void*)&out_tail
    };
    (void)hipLaunchCooperativeKernel(
        reinterpret_cast<const void*>(&moe_fused),
        dim3(256), dim3(512), kargs, 131072, stream);
}